// Round 6
// baseline (264.101 us; speedup 1.0000x reference)
//
#include <hip/hip_runtime.h>
#include <hip/hip_bf16.h>
#include <type_traits>
#include <utility>

// Problem: B=32, P=4, N=1024, C=384.
// softmax over a size-1 axis == 1.0, so:
//   cv[b,p,:]  = (sum_n x[b,p,n,:]) @ Wk + N*bk          (fp32, exact)
//   out        = (relu(x@Wv + bv) * cv) @ Wp + bp        (bf16 MFMA)
// Split pipeline (one x read total):
//   k_val: x -> value' = relu(x@Wv+bv) bf16 (swizzled image in ws) + xsum
//   k_cv : cv from xsum
//   k_out: gate value' by cv[col], GEMM2, + bp -> out
#define C_    384
#define N_    1024
#define G_    128          // B*P groups
#define QKVD  769
#define TILEB 49152        // 64 rows x 384 cols x 2B

typedef float  f32x4 __attribute__((ext_vector_type(4)));
typedef short  s16x8 __attribute__((ext_vector_type(8)));
typedef __bf16 b16x8 __attribute__((ext_vector_type(8)));

template <typename V, typename = void>
struct mfma_takes : std::false_type {};
template <typename V>
struct mfma_takes<V, std::void_t<decltype(__builtin_amdgcn_mfma_f32_16x16x32_bf16(
    std::declval<V>(), std::declval<V>(), std::declval<f32x4>(), 0, 0, 0))>>
    : std::true_type {};

using frag_t = std::conditional_t<mfma_takes<s16x8>::value, s16x8, b16x8>;

template <typename V>
__device__ __forceinline__ f32x4 mfma_bf16(V a, V b, f32x4 c) {
  return __builtin_amdgcn_mfma_f32_16x16x32_bf16(a, b, c, 0, 0, 0);
}

__device__ __forceinline__ unsigned short f2bf(float f) {
  union { float f; unsigned u; } v; v.f = f;
  unsigned r = v.u + 0x7fffu + ((v.u >> 16) & 1u);   // RNE
  return (unsigned short)(r >> 16);
}
__device__ __forceinline__ unsigned pack2(float lo, float hi) {
  return (unsigned)f2bf(lo) | ((unsigned)f2bf(hi) << 16);
}
__device__ __forceinline__ float bf2f(unsigned short b) {
  union { unsigned u; float f; } v; v.u = (unsigned)b << 16;
  return v.f;
}

// ---------------- K2: cv[g][c] = xsum[g]@Wk[:,c] + N*bk[c] ----------------
__global__ void k_cv(const float* __restrict__ xsum, const float* __restrict__ w_qkv,
                     const float* __restrict__ b_qkv, float* __restrict__ cv) {
  __shared__ float xs[C_];
  int g = blockIdx.x, c = threadIdx.x;   // 384 threads
  xs[c] = xsum[g * C_ + c];
  __syncthreads();
  float acc = 0.f;
#pragma unroll 4
  for (int k = 0; k < C_; ++k) acc += xs[k] * w_qkv[k * QKVD + 1 + c];
  cv[g * C_ + c] = acc + (float)N_ * b_qkv[1 + c];
}

// ------- K3: pack Wv (w_qkv[:,385:769]) and Wp (w_proj) as bf16 frag-major -------
// entry (kk,nf,lane) -> 8 bf16 = B[k = kk*32+(lane>>4)*8 + j][n = nf*16+(lane&15)]
__global__ void k_pack(const float* __restrict__ w_qkv, const float* __restrict__ w_proj,
                       unsigned short* __restrict__ pWv, unsigned short* __restrict__ pWp) {
  int bid = blockIdx.x;
  int mat = bid / 288;             // 0: Wv, 1: Wp    (288 = 12 kk * 24 nf)
  int r   = bid % 288;
  int kk = r / 24, nf = r % 24;
  int lane = threadIdx.x;          // 64
  int kbase = kk * 32 + (lane >> 4) * 8;
  int n = nf * 16 + (lane & 15);
  unsigned v[4];
#pragma unroll
  for (int jj = 0; jj < 4; ++jj) {
    int k0 = kbase + jj * 2;
    float f0 = mat ? w_proj[(size_t)k0 * C_ + n]       : w_qkv[(size_t)k0 * QKVD + 385 + n];
    float f1 = mat ? w_proj[(size_t)(k0 + 1) * C_ + n] : w_qkv[(size_t)(k0 + 1) * QKVD + 385 + n];
    v[jj] = (unsigned)f2bf(f0) | ((unsigned)f2bf(f1) << 16);
  }
  unsigned short* dst = (mat ? pWp : pWv) + ((size_t)r * 64 + lane) * 8;
  uint4 w; w.x = v[0]; w.y = v[1]; w.z = v[2]; w.w = v[3];
  *(uint4*)dst = w;
}

// ---------------- K_val: value' = relu(x@Wv + bv) -> bf16 image; + xsum ----------------
// 2048 blocks x 512 thr (8 waves). Block = 64 rows. Wave (wr=wv>>2, wc=wv&3):
// rows wr*32..+32, cols wc*96..+96. acc[2][6] static (rule #20).
__global__ __launch_bounds__(512) void k_val(
    const float* __restrict__ x, const unsigned short* __restrict__ pWv,
    const float* __restrict__ b_qkv, char* __restrict__ vws,
    float* __restrict__ xsum) {
  __shared__ __align__(16) char tile[TILEB];   // 64 x 384 bf16, XOR-swizzled
  __shared__ float csum[C_], bv_l[C_];

  const int tid  = threadIdx.x;
  const int lane = tid & 63;
  const int wv   = tid >> 6;                 // 0..7
  const int R0   = blockIdx.x * 64;
  const int g    = R0 >> 10;

  for (int c = tid; c < C_; c += 512) {
    csum[c] = 0.f;
    bv_l[c] = b_qkv[1 + C_ + c];
  }
  __syncthreads();

  // stage x -> bf16 LDS (swizzled) + exact fp32 column partial sums.
  // threads 0..383: fixed col range c8=(t%48)*8, rows (t/48)*8 + j, j=0..7
  if (tid < 384) {
    const float* xg = x + (size_t)R0 * C_;
    const int c8 = (tid % 48) * 8;
    const int r0 = (tid / 48) * 8;
    float s0=0,s1=0,s2=0,s3=0,s4=0,s5=0,s6=0,s7=0;
#pragma unroll
    for (int j = 0; j < 8; ++j) {
      int row = r0 + j;
      float4 a = *(const float4*)(xg + (size_t)row * C_ + c8);
      float4 b = *(const float4*)(xg + (size_t)row * C_ + c8 + 4);
      uint4 w;
      w.x = pack2(a.x, a.y); w.y = pack2(a.z, a.w);
      w.z = pack2(b.x, b.y); w.w = pack2(b.z, b.w);
      int byte = (row * 768 + c8 * 2) ^ ((row & 7) << 4);
      *(uint4*)(tile + byte) = w;
      s0 += a.x; s1 += a.y; s2 += a.z; s3 += a.w;
      s4 += b.x; s5 += b.y; s6 += b.z; s7 += b.w;
    }
    atomicAdd(&csum[c8 + 0], s0); atomicAdd(&csum[c8 + 1], s1);
    atomicAdd(&csum[c8 + 2], s2); atomicAdd(&csum[c8 + 3], s3);
    atomicAdd(&csum[c8 + 4], s4); atomicAdd(&csum[c8 + 5], s5);
    atomicAdd(&csum[c8 + 6], s6); atomicAdd(&csum[c8 + 7], s7);
  }
  __syncthreads();
  if (tid < 384) atomicAdd(&xsum[g * C_ + tid], csum[tid]);

  // ---- GEMM1: value = x @ Wv ----
  const int wr = wv >> 2, wc = wv & 3;
  const f32x4 zero = {0.f, 0.f, 0.f, 0.f};
  f32x4 acc[2][6];
#pragma unroll
  for (int m = 0; m < 2; ++m)
#pragma unroll
    for (int n = 0; n < 6; ++n) acc[m][n] = zero;

  for (int kk = 0; kk < 12; ++kk) {
    frag_t A[2], Bv[6];
    int kb2 = (kk * 32 + (lane >> 4) * 8) * 2;
#pragma unroll
    for (int m = 0; m < 2; ++m) {
      int row = wr * 32 + m * 16 + (lane & 15);
      A[m] = *(const frag_t*)(tile + ((row * 768 + kb2) ^ ((row & 7) << 4)));
    }
    const unsigned short* bp_ = pWv + ((size_t)(kk * 24 + wc * 6) * 64 + lane) * 8;
#pragma unroll
    for (int n = 0; n < 6; ++n) Bv[n] = *(const frag_t*)(bp_ + (size_t)n * 64 * 8);
#pragma unroll
    for (int m = 0; m < 2; ++m)
#pragma unroll
      for (int n = 0; n < 6; ++n) acc[m][n] = mfma_bf16(A[m], Bv[n], acc[m][n]);
  }
  __syncthreads();   // all waves done reading x tile

  // ---- epilogue: relu(value + bv) -> bf16 -> same LDS tile ----
#pragma unroll
  for (int m = 0; m < 2; ++m) {
#pragma unroll
    for (int n = 0; n < 6; ++n) {
      int col = wc * 96 + n * 16 + (lane & 15);
      float bvv = bv_l[col];
#pragma unroll
      for (int r = 0; r < 4; ++r) {
        int row = wr * 32 + m * 16 + (lane >> 4) * 4 + r;   // verified C/D layout
        float val = fmaxf(acc[m][n][r] + bvv, 0.f);
        *(unsigned short*)(tile + ((row * 768 + col * 2) ^ ((row & 7) << 4))) = f2bf(val);
      }
    }
  }
  __syncthreads();

  // ---- dump swizzled LDS image linearly to ws (fully coalesced) ----
  const uint4* st = (const uint4*)tile;
  uint4* dst = (uint4*)(vws + (size_t)blockIdx.x * TILEB);
#pragma unroll
  for (int j = 0; j < 6; ++j) {
    int idx = tid + j * 512;       // 3072 chunks of 16B
    dst[idx] = st[idx];
  }
}

// ---------------- K_out: gated = value' * cv[col]; out = gated@Wp + bp ----------------
// 2048 blocks x 512 thr; same geometry as k_val.
__global__ __launch_bounds__(512) void k_out(
    const char* __restrict__ vws, const unsigned short* __restrict__ pWp,
    const float* __restrict__ cv, const float* __restrict__ b_proj,
    float* __restrict__ out) {
  __shared__ __align__(16) char tile[TILEB];
  __shared__ float cv_l[C_], bp_l[C_];

  const int tid  = threadIdx.x;
  const int lane = tid & 63;
  const int wv   = tid >> 6;
  const int R0   = blockIdx.x * 64;
  const int g    = R0 >> 10;

  for (int c = tid; c < C_; c += 512) {
    cv_l[c] = cv[g * C_ + c];
    bp_l[c] = b_proj[c];
  }
  __syncthreads();

  // stage-gate: load linear swizzled image, scale by cv[col], write back linear.
  // chunk idx -> row = idx/48; within-chunk cols are 8 consecutive starting at
  // col0 = ((L%768) ^ ((row&7)<<4)) / 2  (swizzle is 16B-granular).
  {
    const uint4* src = (const uint4*)(vws + (size_t)blockIdx.x * TILEB);
    uint4* dt = (uint4*)tile;
#pragma unroll
    for (int j = 0; j < 6; ++j) {
      int idx = tid + j * 512;
      int row = idx / 48;
      int off = ((idx % 48) * 16) ^ ((row & 7) << 4);
      int col0 = off >> 1;
      uint4 w = src[idx];
      unsigned d[4] = {w.x, w.y, w.z, w.w};
      unsigned o[4];
#pragma unroll
      for (int q = 0; q < 4; ++q) {
        float lo = bf2f((unsigned short)(d[q] & 0xffffu)) * cv_l[col0 + 2 * q];
        float hi = bf2f((unsigned short)(d[q] >> 16))     * cv_l[col0 + 2 * q + 1];
        o[q] = pack2(lo, hi);
      }
      uint4 ww; ww.x = o[0]; ww.y = o[1]; ww.z = o[2]; ww.w = o[3];
      dt[idx] = ww;
    }
  }
  __syncthreads();

  // ---- GEMM2: out = gated @ Wp ----
  const int wr = wv >> 2, wc = wv & 3;
  const f32x4 zero = {0.f, 0.f, 0.f, 0.f};
  f32x4 acc[2][6];
#pragma unroll
  for (int m = 0; m < 2; ++m)
#pragma unroll
    for (int n = 0; n < 6; ++n) acc[m][n] = zero;

  for (int kk = 0; kk < 12; ++kk) {
    frag_t A[2], Bv[6];
    int kb2 = (kk * 32 + (lane >> 4) * 8) * 2;
#pragma unroll
    for (int m = 0; m < 2; ++m) {
      int row = wr * 32 + m * 16 + (lane & 15);
      A[m] = *(const frag_t*)(tile + ((row * 768 + kb2) ^ ((row & 7) << 4)));
    }
    const unsigned short* bp_ = pWp + ((size_t)(kk * 24 + wc * 6) * 64 + lane) * 8;
#pragma unroll
    for (int n = 0; n < 6; ++n) Bv[n] = *(const frag_t*)(bp_ + (size_t)n * 64 * 8);
#pragma unroll
    for (int m = 0; m < 2; ++m)
#pragma unroll
      for (int n = 0; n < 6; ++n) acc[m][n] = mfma_bf16(A[m], Bv[n], acc[m][n]);
  }

  // ---- epilogue: out = acc + bp ----
#pragma unroll
  for (int m = 0; m < 2; ++m) {
#pragma unroll
    for (int n = 0; n < 6; ++n) {
      int col = wc * 96 + n * 16 + (lane & 15);
      float bpv = bp_l[col];
#pragma unroll
      for (int r = 0; r < 4; ++r) {
        int row = wr * 32 + m * 16 + (lane >> 4) * 4 + r;
        out[(size_t)(R0 + row) * C_ + col] = acc[m][n][r] + bpv;
      }
    }
  }
}

extern "C" void kernel_launch(void* const* d_in, const int* in_sizes, int n_in,
                              void* d_out, int out_size, void* d_ws, size_t ws_size,
                              hipStream_t stream) {
  const float* x      = (const float*)d_in[0];
  const float* w_qkv  = (const float*)d_in[1];
  const float* b_qkv  = (const float*)d_in[2];
  const float* w_proj = (const float*)d_in[3];
  const float* b_proj = (const float*)d_in[4];
  float* out = (float*)d_out;

  // ws: xsum[128*384 f] | cv[128*384 f] | pWv[147456 u16] | pWp[147456 u16] | vws[~96MB]
  float* xsum = (float*)d_ws;
  float* cvp  = xsum + G_ * C_;
  unsigned short* pWv = (unsigned short*)(cvp + G_ * C_);
  unsigned short* pWp = pWv + C_ * C_;
  char* vws = (char*)(pWp + C_ * C_);

  hipMemsetAsync(xsum, 0, G_ * C_ * sizeof(float), stream);
  k_pack<<<576, 64, 0, stream>>>(w_qkv, w_proj, pWv, pWp);
  k_val<<<2048, 512, 0, stream>>>(x, pWv, b_qkv, vws, xsum);
  k_cv<<<G_, C_, 0, stream>>>(xsum, w_qkv, b_qkv, cvp);
  k_out<<<2048, 512, 0, stream>>>(vws, pWp, cvp, b_proj, out);
}

// Round 7
// 261.683 us; speedup vs baseline: 1.0092x; 1.0092x over previous
//
#include <hip/hip_runtime.h>
#include <hip/hip_bf16.h>
#include <type_traits>
#include <utility>

// Problem: B=32, P=4, N=1024, C=384.
// softmax over a size-1 axis == 1.0, so:
//   cv[b,p,:]  = (sum_n x[b,p,n,:]) @ Wk + N*bk          (fp32, exact)
//   out        = (relu(x@Wv + bv) * cv) @ Wp + bp        (bf16 MFMA, fused)
#define C_    384
#define N_    1024
#define G_    128          // B*P groups
#define QKVD  769

typedef float  f32x4 __attribute__((ext_vector_type(4)));
typedef short  s16x8 __attribute__((ext_vector_type(8)));
typedef __bf16 b16x8 __attribute__((ext_vector_type(8)));

template <typename V, typename = void>
struct mfma_takes : std::false_type {};
template <typename V>
struct mfma_takes<V, std::void_t<decltype(__builtin_amdgcn_mfma_f32_16x16x32_bf16(
    std::declval<V>(), std::declval<V>(), std::declval<f32x4>(), 0, 0, 0))>>
    : std::true_type {};

using frag_t = std::conditional_t<mfma_takes<s16x8>::value, s16x8, b16x8>;

template <typename V>
__device__ __forceinline__ f32x4 mfma_bf16(V a, V b, f32x4 c) {
  return __builtin_amdgcn_mfma_f32_16x16x32_bf16(a, b, c, 0, 0, 0);
}

__device__ __forceinline__ unsigned short f2bf(float f) {
  union { float f; unsigned u; } v; v.f = f;
  unsigned r = v.u + 0x7fffu + ((v.u >> 16) & 1u);   // RNE
  return (unsigned short)(r >> 16);
}
__device__ __forceinline__ unsigned pack2(float lo, float hi) {
  return (unsigned)f2bf(lo) | ((unsigned)f2bf(hi) << 16);
}

// ---------------- K1: xsum[g][c] = sum_n x[g][n][c]  (float4, LDS-reduced) ----------------
__global__ __launch_bounds__(384) void k_xsum(const float* __restrict__ x,
                                              float* __restrict__ xsum) {
  __shared__ float sh[4][C_];
  const int tid = threadIdx.x;
  const int c4  = (tid % 96) * 4;
  const int rg  = tid / 96;            // 0..3
  const int b   = blockIdx.x;          // 1024
  const int g   = b >> 3;
  const float* p = x + ((size_t)b * 128 + (size_t)rg * 32) * C_ + c4;
  f32x4 s = {0.f, 0.f, 0.f, 0.f};
#pragma unroll 8
  for (int r = 0; r < 32; ++r) {
    float4 v = *(const float4*)(p + (size_t)r * C_);
    s.x += v.x; s.y += v.y; s.z += v.z; s.w += v.w;
  }
  *(f32x4*)&sh[rg][c4] = s;
  __syncthreads();
  if (rg == 0) {
#pragma unroll
    for (int j = 0; j < 4; ++j) {
      float v = sh[0][c4 + j] + sh[1][c4 + j] + sh[2][c4 + j] + sh[3][c4 + j];
      atomicAdd(&xsum[g * C_ + c4 + j], v);
    }
  }
}

// ---------------- K2: cv[g][c] = xsum[g]@Wk[:,c] + N*bk[c] ----------------
__global__ void k_cv(const float* __restrict__ xsum, const float* __restrict__ w_qkv,
                     const float* __restrict__ b_qkv, float* __restrict__ cv) {
  __shared__ float xs[C_];
  int g = blockIdx.x, c = threadIdx.x;   // 384 threads
  xs[c] = xsum[g * C_ + c];
  __syncthreads();
  float acc = 0.f;
#pragma unroll 4
  for (int k = 0; k < C_; ++k) acc += xs[k] * w_qkv[k * QKVD + 1 + c];
  cv[g * C_ + c] = acc + (float)N_ * b_qkv[1 + c];
}

// ------- K3: pack Wv (w_qkv[:,385:769]) and Wp (w_proj) as bf16 frag-major -------
// entry (kk,nf,lane) -> 8 bf16 = B[k = kk*32+(lane>>4)*8 + j][n = nf*16+(lane&15)]
__global__ void k_pack(const float* __restrict__ w_qkv, const float* __restrict__ w_proj,
                       unsigned short* __restrict__ pWv, unsigned short* __restrict__ pWp) {
  int bid = blockIdx.x;
  int mat = bid / 288;             // 0: Wv, 1: Wp    (288 = 12 kk * 24 nf)
  int r   = bid % 288;
  int kk = r / 24, nf = r % 24;
  int lane = threadIdx.x;          // 64
  int kbase = kk * 32 + (lane >> 4) * 8;
  int n = nf * 16 + (lane & 15);
  unsigned v[4];
#pragma unroll
  for (int jj = 0; jj < 4; ++jj) {
    int k0 = kbase + jj * 2;
    float f0 = mat ? w_proj[(size_t)k0 * C_ + n]       : w_qkv[(size_t)k0 * QKVD + 385 + n];
    float f1 = mat ? w_proj[(size_t)(k0 + 1) * C_ + n] : w_qkv[(size_t)(k0 + 1) * QKVD + 385 + n];
    v[jj] = (unsigned)f2bf(f0) | ((unsigned)f2bf(f1) << 16);
  }
  unsigned short* dst = (mat ? pWp : pWv) + ((size_t)r * 64 + lane) * 8;
  uint4 w; w.x = v[0]; w.y = v[1]; w.z = v[2]; w.w = v[3];
  *(uint4*)dst = w;
}

// ---------------- K4: fused value-GEMM -> relu*cv -> proj-GEMM ----------------
// 4096 blocks x 256 thr (4 waves). Block = 32 rows x 384 cols.
// Wave w: all 32 rows x cols [w*96, w*96+96). Explicit 2-deep software pipeline
// in both GEMM K-loops (all register names static — rule #20).
__global__ __launch_bounds__(256) void k_fused(
    const float* __restrict__ x, const unsigned short* __restrict__ pWv,
    const unsigned short* __restrict__ pWp, const float* __restrict__ cv,
    const float* __restrict__ b_qkv, const float* __restrict__ b_proj,
    float* __restrict__ out) {
  __shared__ __align__(16) char tile[32 * 768];   // 32 rows x 384 bf16, XOR-swizzled
  __shared__ float cv_l[C_], bv_l[C_], bp_l[C_];

  const int tid  = threadIdx.x;
  const int lane = tid & 63;
  const int wv   = tid >> 6;                 // 0..3
  const int R0   = blockIdx.x * 32;
  const int g    = R0 >> 10;

  for (int c = tid; c < C_; c += 256) {
    cv_l[c] = cv[g * C_ + c];
    bv_l[c] = b_qkv[1 + C_ + c];
    bp_l[c] = b_proj[c];
  }

  // stage 32x384 fp32 -> bf16 -> LDS (swizzle: byte off ^= (row&7)<<4)
  {
    const float* xg = x + (size_t)R0 * C_;
#pragma unroll
    for (int j = 0; j < 6; ++j) {
      int ch  = tid + j * 256;          // 1536 chunks of 8 f32
      int row = ch / 48;
      int c8  = (ch % 48) * 8;          // element col
      const float4* s0 = (const float4*)(xg + (size_t)row * C_ + c8);
      float4 a = s0[0], b = s0[1];
      uint4 w;
      w.x = pack2(a.x, a.y); w.y = pack2(a.z, a.w);
      w.z = pack2(b.x, b.y); w.w = pack2(b.z, b.w);
      int byte = (row * 768 + c8 * 2) ^ ((row & 7) << 4);
      *(uint4*)(tile + byte) = w;
    }
  }
  __syncthreads();

  const f32x4 zero = {0.f, 0.f, 0.f, 0.f};
  f32x4 acc[2][6];
#pragma unroll
  for (int m = 0; m < 2; ++m)
#pragma unroll
    for (int n = 0; n < 6; ++n) acc[m][n] = zero;

// A-frags for K-chunk KK (from swizzled LDS tile)
#define LDA(A0_, A1_, KK)                                                      \
  do {                                                                         \
    int kb2_ = ((KK) * 32 + (lane >> 4) * 8) * 2;                              \
    int r0_  = (lane & 15);                                                    \
    int r1_  = 16 + r0_;                                                       \
    A0_ = *(const frag_t*)(tile + ((r0_ * 768 + kb2_) ^ ((r0_ & 7) << 4)));    \
    A1_ = *(const frag_t*)(tile + ((r1_ * 768 + kb2_) ^ ((r1_ & 7) << 4)));    \
  } while (0)

// B-frags (6) for K-chunk KK from packed weights PW
#define LDB(B0_, B1_, B2_, B3_, B4_, B5_, PW, KK)                              \
  do {                                                                         \
    const unsigned short* bp__ =                                               \
        (PW) + ((size_t)((KK) * 24 + wv * 6) * 64 + lane) * 8;                 \
    B0_ = *(const frag_t*)(bp__ + 0 * 512);                                    \
    B1_ = *(const frag_t*)(bp__ + 1 * 512);                                    \
    B2_ = *(const frag_t*)(bp__ + 2 * 512);                                    \
    B3_ = *(const frag_t*)(bp__ + 3 * 512);                                    \
    B4_ = *(const frag_t*)(bp__ + 4 * 512);                                    \
    B5_ = *(const frag_t*)(bp__ + 5 * 512);                                    \
  } while (0)

// 12 MFMAs: 2 row-frags x 6 col-frags (acc indices are literals)
#define MM12(A0_, A1_, B0_, B1_, B2_, B3_, B4_, B5_)                           \
  do {                                                                         \
    acc[0][0] = mfma_bf16(A0_, B0_, acc[0][0]);                                \
    acc[1][0] = mfma_bf16(A1_, B0_, acc[1][0]);                                \
    acc[0][1] = mfma_bf16(A0_, B1_, acc[0][1]);                                \
    acc[1][1] = mfma_bf16(A1_, B1_, acc[1][1]);                                \
    acc[0][2] = mfma_bf16(A0_, B2_, acc[0][2]);                                \
    acc[1][2] = mfma_bf16(A1_, B2_, acc[1][2]);                                \
    acc[0][3] = mfma_bf16(A0_, B3_, acc[0][3]);                                \
    acc[1][3] = mfma_bf16(A1_, B3_, acc[1][3]);                                \
    acc[0][4] = mfma_bf16(A0_, B4_, acc[0][4]);                                \
    acc[1][4] = mfma_bf16(A1_, B4_, acc[1][4]);                                \
    acc[0][5] = mfma_bf16(A0_, B5_, acc[0][5]);                                \
    acc[1][5] = mfma_bf16(A1_, B5_, acc[1][5]);                                \
  } while (0)

// 2-deep pipelined GEMM over 12 K-chunks (kk pairs; all names static)
#define GEMM_PIPE(PW)                                                          \
  do {                                                                         \
    frag_t Aa0, Aa1, Ab0, Ab1;                                                 \
    frag_t Ba0, Ba1, Ba2, Ba3, Ba4, Ba5;                                       \
    frag_t Bb0, Bb1, Bb2, Bb3, Bb4, Bb5;                                       \
    LDA(Aa0, Aa1, 0);                                                          \
    LDB(Ba0, Ba1, Ba2, Ba3, Ba4, Ba5, PW, 0);                                  \
    _Pragma("unroll") for (int kkp = 0; kkp < 6; ++kkp) {                      \
      const int kk0 = 2 * kkp;                                                 \
      LDA(Ab0, Ab1, kk0 + 1);                                                  \
      LDB(Bb0, Bb1, Bb2, Bb3, Bb4, Bb5, PW, kk0 + 1);                          \
      MM12(Aa0, Aa1, Ba0, Ba1, Ba2, Ba3, Ba4, Ba5);                            \
      if (kkp < 5) {                                                           \
        LDA(Aa0, Aa1, kk0 + 2);                                                \
        LDB(Ba0, Ba1, Ba2, Ba3, Ba4, Ba5, PW, kk0 + 2);                        \
      }                                                                        \
      MM12(Ab0, Ab1, Bb0, Bb1, Bb2, Bb3, Bb4, Bb5);                            \
    }                                                                          \
  } while (0)

  // ---- GEMM1: value = x @ Wv ----
  GEMM_PIPE(pWv);
  __syncthreads();   // all waves done reading x tile

  // ---- epilogue1: gated = relu(value + bv) * cv -> bf16 -> same LDS tile ----
#pragma unroll
  for (int m = 0; m < 2; ++m) {
#pragma unroll
    for (int n = 0; n < 6; ++n) {
      int col = wv * 96 + n * 16 + (lane & 15);
      float cvv = cv_l[col], bvv = bv_l[col];
#pragma unroll
      for (int r = 0; r < 4; ++r) {
        int row = m * 16 + (lane >> 4) * 4 + r;   // verified C/D layout
        float val = fmaxf(acc[m][n][r] + bvv, 0.f) * cvv;
        *(unsigned short*)(tile + ((row * 768 + col * 2) ^ ((row & 7) << 4))) = f2bf(val);
      }
    }
  }
  __syncthreads();   // gated tile complete

  // ---- GEMM2: out = gated @ Wp ----
#pragma unroll
  for (int m = 0; m < 2; ++m)
#pragma unroll
    for (int n = 0; n < 6; ++n) acc[m][n] = zero;

  GEMM_PIPE(pWp);

  // ---- epilogue2: out = acc + bp ----
#pragma unroll
  for (int m = 0; m < 2; ++m) {
#pragma unroll
    for (int n = 0; n < 6; ++n) {
      int col = wv * 96 + n * 16 + (lane & 15);
      float bpv = bp_l[col];
#pragma unroll
      for (int r = 0; r < 4; ++r) {
        int row = m * 16 + (lane >> 4) * 4 + r;
        out[(size_t)(R0 + row) * C_ + col] = acc[m][n][r] + bpv;
      }
    }
  }
#undef LDA
#undef LDB
#undef MM12
#undef GEMM_PIPE
}

extern "C" void kernel_launch(void* const* d_in, const int* in_sizes, int n_in,
                              void* d_out, int out_size, void* d_ws, size_t ws_size,
                              hipStream_t stream) {
  const float* x      = (const float*)d_in[0];
  const float* w_qkv  = (const float*)d_in[1];
  const float* b_qkv  = (const float*)d_in[2];
  const float* w_proj = (const float*)d_in[3];
  const float* b_proj = (const float*)d_in[4];
  float* out = (float*)d_out;

  // ws: xsum[128*384 f] | cv[128*384 f] | pWv[147456 bf16] | pWp[147456 bf16]  (~1 MB)
  float* xsum = (float*)d_ws;
  float* cvp  = xsum + G_ * C_;
  unsigned short* pWv = (unsigned short*)(cvp + G_ * C_);
  unsigned short* pWp = pWv + C_ * C_;

  hipMemsetAsync(xsum, 0, G_ * C_ * sizeof(float), stream);
  k_xsum<<<1024, 384, 0, stream>>>(x, xsum);        // also warms L3 with x
  k_pack<<<576, 64, 0, stream>>>(w_qkv, w_proj, pWv, pWp);
  k_cv<<<G_, C_, 0, stream>>>(xsum, w_qkv, b_qkv, cvp);
  k_fused<<<4096, 256, 0, stream>>>(x, pWv, pWp, cvp, b_qkv, b_proj, out);
}

// Round 8
// 243.495 us; speedup vs baseline: 1.0846x; 1.0747x over previous
//
#include <hip/hip_runtime.h>
#include <hip/hip_bf16.h>
#include <type_traits>
#include <utility>

// Problem: B=32, P=4, N=1024, C=384.
// softmax over a size-1 axis == 1.0, so:
//   cv[b,p,:]  = (sum_n x[b,p,n,:]) @ Wk + N*bk          (fp32, exact)
//   out        = (relu(x@Wv + bv) * cv) @ Wp + bp        (bf16 MFMA, fused)
#define C_    384
#define N_    1024
#define G_    128          // B*P groups
#define QKVD  769

typedef float  f32x4 __attribute__((ext_vector_type(4)));
typedef short  s16x8 __attribute__((ext_vector_type(8)));
typedef __bf16 b16x8 __attribute__((ext_vector_type(8)));

template <typename V, typename = void>
struct mfma_takes : std::false_type {};
template <typename V>
struct mfma_takes<V, std::void_t<decltype(__builtin_amdgcn_mfma_f32_16x16x32_bf16(
    std::declval<V>(), std::declval<V>(), std::declval<f32x4>(), 0, 0, 0))>>
    : std::true_type {};

using frag_t = std::conditional_t<mfma_takes<s16x8>::value, s16x8, b16x8>;

template <typename V>
__device__ __forceinline__ f32x4 mfma_bf16(V a, V b, f32x4 c) {
  return __builtin_amdgcn_mfma_f32_16x16x32_bf16(a, b, c, 0, 0, 0);
}

__device__ __forceinline__ unsigned short f2bf(float f) {
  union { float f; unsigned u; } v; v.f = f;
  unsigned r = v.u + 0x7fffu + ((v.u >> 16) & 1u);   // RNE
  return (unsigned short)(r >> 16);
}
__device__ __forceinline__ unsigned pack2(float lo, float hi) {
  return (unsigned)f2bf(lo) | ((unsigned)f2bf(hi) << 16);
}

// ---------------- K1: xsum[g][c] = sum_n x[g][n][c]  (float4, LDS-reduced) ----------------
__global__ __launch_bounds__(384) void k_xsum(const float* __restrict__ x,
                                              float* __restrict__ xsum) {
  __shared__ float sh[4][C_];
  const int tid = threadIdx.x;
  const int c4  = (tid % 96) * 4;
  const int rg  = tid / 96;            // 0..3
  const int b   = blockIdx.x;          // 1024
  const int g   = b >> 3;
  const float* p = x + ((size_t)b * 128 + (size_t)rg * 32) * C_ + c4;
  f32x4 s = {0.f, 0.f, 0.f, 0.f};
#pragma unroll 8
  for (int r = 0; r < 32; ++r) {
    float4 v = *(const float4*)(p + (size_t)r * C_);
    s.x += v.x; s.y += v.y; s.z += v.z; s.w += v.w;
  }
  *(f32x4*)&sh[rg][c4] = s;
  __syncthreads();
  if (rg == 0) {
#pragma unroll
    for (int j = 0; j < 4; ++j) {
      float v = sh[0][c4 + j] + sh[1][c4 + j] + sh[2][c4 + j] + sh[3][c4 + j];
      atomicAdd(&xsum[g * C_ + c4 + j], v);
    }
  }
}

// ---------------- K2: cv[g][c] = xsum[g]@Wk[:,c] + N*bk[c] ----------------
__global__ void k_cv(const float* __restrict__ xsum, const float* __restrict__ w_qkv,
                     const float* __restrict__ b_qkv, float* __restrict__ cv) {
  __shared__ float xs[C_];
  int g = blockIdx.x, c = threadIdx.x;   // 384 threads
  xs[c] = xsum[g * C_ + c];
  __syncthreads();
  float acc = 0.f;
#pragma unroll 4
  for (int k = 0; k < C_; ++k) acc += xs[k] * w_qkv[k * QKVD + 1 + c];
  cv[g * C_ + c] = acc + (float)N_ * b_qkv[1 + c];
}

// ------- K3: pack Wv (w_qkv[:,385:769]) and Wp (w_proj) as bf16 frag-major -------
// entry (kk,nf,lane) -> 8 bf16 = B[k = kk*32+(lane>>4)*8 + j][n = nf*16+(lane&15)]
__global__ void k_pack(const float* __restrict__ w_qkv, const float* __restrict__ w_proj,
                       unsigned short* __restrict__ pWv, unsigned short* __restrict__ pWp) {
  int bid = blockIdx.x;
  int mat = bid / 288;             // 0: Wv, 1: Wp    (288 = 12 kk * 24 nf)
  int r   = bid % 288;
  int kk = r / 24, nf = r % 24;
  int lane = threadIdx.x;          // 64
  int kbase = kk * 32 + (lane >> 4) * 8;
  int n = nf * 16 + (lane & 15);
  unsigned v[4];
#pragma unroll
  for (int jj = 0; jj < 4; ++jj) {
    int k0 = kbase + jj * 2;
    float f0 = mat ? w_proj[(size_t)k0 * C_ + n]       : w_qkv[(size_t)k0 * QKVD + 385 + n];
    float f1 = mat ? w_proj[(size_t)(k0 + 1) * C_ + n] : w_qkv[(size_t)(k0 + 1) * QKVD + 385 + n];
    v[jj] = (unsigned)f2bf(f0) | ((unsigned)f2bf(f1) << 16);
  }
  unsigned short* dst = (mat ? pWp : pWv) + ((size_t)r * 64 + lane) * 8;
  uint4 w; w.x = v[0]; w.y = v[1]; w.z = v[2]; w.w = v[3];
  *(uint4*)dst = w;
}

// ---------------- K4: fused value-GEMM -> relu*cv -> proj-GEMM ----------------
// 2048 blocks x 512 thr (8 waves). Block = 64 rows x 384 cols.
// Wave w: ALL 64 rows x cols [w*48, w*48+48)  -> acc[4][3] (48 VGPR), and B-frag
// traffic per output row is HALF of the 32-rows-per-wave version (L2 floor 68->34us).
// cv/bv/bp kept in 9 per-thread regs (each thread touches exactly 3 cols).
// All register indices compile-time (rule #20).
__global__ __launch_bounds__(512) void k_fused(
    const float* __restrict__ x, const unsigned short* __restrict__ pWv,
    const unsigned short* __restrict__ pWp, const float* __restrict__ cv,
    const float* __restrict__ b_qkv, const float* __restrict__ b_proj,
    float* __restrict__ out) {
  __shared__ __align__(16) char tile[64 * 768];   // 64 rows x 384 bf16, XOR-swizzled

  const int tid  = threadIdx.x;
  const int lane = tid & 63;
  const int wv   = tid >> 6;                 // 0..7
  const int R0   = blockIdx.x * 64;
  const int g    = R0 >> 10;

  // per-thread epilogue constants: 3 columns (n = 0..2)
  float cvr[3], bvr[3], bpr[3];
#pragma unroll
  for (int n = 0; n < 3; ++n) {
    int col = wv * 48 + n * 16 + (lane & 15);
    cvr[n] = cv[g * C_ + col];
    bvr[n] = b_qkv[1 + C_ + col];
    bpr[n] = b_proj[col];
  }

  // stage 64x384 fp32 -> bf16 -> LDS (swizzle: byte off ^= (row&7)<<4)
  {
    const float* xg = x + (size_t)R0 * C_;
#pragma unroll
    for (int j = 0; j < 6; ++j) {
      int ch  = tid + j * 512;          // 3072 chunks of 8 f32
      int row = ch / 48;
      int c8  = (ch % 48) * 8;          // element col
      const float4* s0 = (const float4*)(xg + (size_t)row * C_ + c8);
      float4 a = s0[0], b = s0[1];
      uint4 w;
      w.x = pack2(a.x, a.y); w.y = pack2(a.z, a.w);
      w.z = pack2(b.x, b.y); w.w = pack2(b.z, b.w);
      int byte = (row * 768 + c8 * 2) ^ ((row & 7) << 4);
      *(uint4*)(tile + byte) = w;
    }
  }
  __syncthreads();

  const f32x4 zero = {0.f, 0.f, 0.f, 0.f};
  f32x4 acc[4][3];
#pragma unroll
  for (int m = 0; m < 4; ++m)
#pragma unroll
    for (int n = 0; n < 3; ++n) acc[m][n] = zero;

  // ---- GEMM1: value = x @ Wv ----
  for (int kk = 0; kk < 12; ++kk) {
    frag_t A[4], Bv[3];
    int kb2 = (kk * 32 + (lane >> 4) * 8) * 2;
#pragma unroll
    for (int m = 0; m < 4; ++m) {
      int row = m * 16 + (lane & 15);
      A[m] = *(const frag_t*)(tile + ((row * 768 + kb2) ^ ((row & 7) << 4)));
    }
    const unsigned short* bp_ = pWv + ((size_t)(kk * 24 + wv * 3) * 64 + lane) * 8;
#pragma unroll
    for (int n = 0; n < 3; ++n) Bv[n] = *(const frag_t*)(bp_ + (size_t)n * 64 * 8);
#pragma unroll
    for (int m = 0; m < 4; ++m)
#pragma unroll
      for (int n = 0; n < 3; ++n) acc[m][n] = mfma_bf16(A[m], Bv[n], acc[m][n]);
  }
  __syncthreads();   // all waves done reading x tile

  // ---- epilogue1: gated = relu(value + bv) * cv -> bf16 -> same LDS tile ----
#pragma unroll
  for (int m = 0; m < 4; ++m) {
#pragma unroll
    for (int n = 0; n < 3; ++n) {
      int col = wv * 48 + n * 16 + (lane & 15);
#pragma unroll
      for (int r = 0; r < 4; ++r) {
        int row = m * 16 + (lane >> 4) * 4 + r;   // verified C/D layout
        float val = fmaxf(acc[m][n][r] + bvr[n], 0.f) * cvr[n];
        *(unsigned short*)(tile + ((row * 768 + col * 2) ^ ((row & 7) << 4))) = f2bf(val);
      }
    }
  }
  __syncthreads();   // gated tile complete

  // ---- GEMM2: out = gated @ Wp ----
#pragma unroll
  for (int m = 0; m < 4; ++m)
#pragma unroll
    for (int n = 0; n < 3; ++n) acc[m][n] = zero;

  for (int kk = 0; kk < 12; ++kk) {
    frag_t A[4], Bv[3];
    int kb2 = (kk * 32 + (lane >> 4) * 8) * 2;
#pragma unroll
    for (int m = 0; m < 4; ++m) {
      int row = m * 16 + (lane & 15);
      A[m] = *(const frag_t*)(tile + ((row * 768 + kb2) ^ ((row & 7) << 4)));
    }
    const unsigned short* bp_ = pWp + ((size_t)(kk * 24 + wv * 3) * 64 + lane) * 8;
#pragma unroll
    for (int n = 0; n < 3; ++n) Bv[n] = *(const frag_t*)(bp_ + (size_t)n * 64 * 8);
#pragma unroll
    for (int m = 0; m < 4; ++m)
#pragma unroll
      for (int n = 0; n < 3; ++n) acc[m][n] = mfma_bf16(A[m], Bv[n], acc[m][n]);
  }

  // ---- epilogue2: out = acc + bp ----
#pragma unroll
  for (int m = 0; m < 4; ++m) {
#pragma unroll
    for (int n = 0; n < 3; ++n) {
      int col = wv * 48 + n * 16 + (lane & 15);
#pragma unroll
      for (int r = 0; r < 4; ++r) {
        int row = m * 16 + (lane >> 4) * 4 + r;
        out[(size_t)(R0 + row) * C_ + col] = acc[m][n][r] + bpr[n];
      }
    }
  }
}

extern "C" void kernel_launch(void* const* d_in, const int* in_sizes, int n_in,
                              void* d_out, int out_size, void* d_ws, size_t ws_size,
                              hipStream_t stream) {
  const float* x      = (const float*)d_in[0];
  const float* w_qkv  = (const float*)d_in[1];
  const float* b_qkv  = (const float*)d_in[2];
  const float* w_proj = (const float*)d_in[3];
  const float* b_proj = (const float*)d_in[4];
  float* out = (float*)d_out;

  // ws: xsum[128*384 f] | cv[128*384 f] | pWv[147456 bf16] | pWp[147456 bf16]  (~1 MB)
  float* xsum = (float*)d_ws;
  float* cvp  = xsum + G_ * C_;
  unsigned short* pWv = (unsigned short*)(cvp + G_ * C_);
  unsigned short* pWp = pWv + C_ * C_;

  hipMemsetAsync(xsum, 0, G_ * C_ * sizeof(float), stream);
  k_xsum<<<1024, 384, 0, stream>>>(x, xsum);        // also warms L3 with x
  k_pack<<<576, 64, 0, stream>>>(w_qkv, w_proj, pWv, pWp);
  k_cv<<<G_, C_, 0, stream>>>(xsum, w_qkv, b_qkv, cvp);
  k_fused<<<2048, 512, 0, stream>>>(x, pWv, pWp, cvp, b_qkv, b_proj, out);
}